// Round 6
// baseline (620.150 us; speedup 1.0000x reference)
//
#include <hip/hip_runtime.h>
#include <hip/hip_bf16.h>
#include <stdint.h>

// Problem constants (from reference)
#define N_NODES  4096
#define EMB_DIM  512
#define N_HEADS  8
#define K_SPARSE 128
#define HEAD_DIM 64   // EMB_DIM / N_HEADS

#define ROWS_PER_BLOCK 16
#define SCATTER_BLOCKS (N_HEADS * N_NODES / ROWS_PER_BLOCK)   // 2048

typedef __attribute__((ext_vector_type(8))) __bf16 bf16x8;
typedef __attribute__((ext_vector_type(4))) float  f32x4;

__device__ __forceinline__ float bf2f(unsigned short u) {
    union { unsigned int i; float f; } v;
    v.i = ((unsigned int)u) << 16;
    return v.f;
}

__device__ __forceinline__ unsigned short f2bf(float f) {
    // round-to-nearest-even fp32 -> bf16
    union { float f; unsigned int i; } v;
    v.f = f;
    unsigned int x = v.i;
    unsigned int rounding = 0x7fffu + ((x >> 16) & 1u);
    x += rounding;
    return (unsigned short)(x >> 16);
}

// raw workgroup barrier WITHOUT the implicit s_waitcnt vmcnt(0) that
// __syncthreads() emits (that drain is exactly what serializes stores).
// lgkmcnt(0) orders this wave's LDS ops; the empty asm after the barrier
// is a compiler-only fence so DS ops can't be hoisted above it.
__device__ __forceinline__ void lds_barrier() {
    asm volatile("s_waitcnt lgkmcnt(0)" ::: "memory");
    __builtin_amdgcn_s_barrier();
    asm volatile("" ::: "memory");
}

// ---------------------------------------------------------------------------
// Kernel 1: fused Q/K projection GEMM, fp32 inputs -> bf16 outputs.
// (unchanged from verified version)
// ---------------------------------------------------------------------------
__global__ __launch_bounds__(256) void proj_kernel(
    const float* __restrict__ X,
    const float* __restrict__ Wq, const float* __restrict__ bq,
    const float* __restrict__ Wk, const float* __restrict__ bk,
    unsigned short* __restrict__ Qb, unsigned short* __restrict__ Kb)
{
    __shared__ unsigned short As[64][40];    // 64 rows x 32 bf16 (+pad)
    __shared__ unsigned short Bs[128][40];   // 128 rows x 32 bf16 (+pad)

    const float* __restrict__ W    = blockIdx.z ? Wk : Wq;
    const float* __restrict__ bias = blockIdx.z ? bk : bq;
    unsigned short* __restrict__ out = blockIdx.z ? Kb : Qb;

    const int t    = threadIdx.x;
    const int M0   = blockIdx.x * 64;
    const int N0   = blockIdx.y * 128;
    const int lane = t & 63;
    const int wave = t >> 6;
    const int wm   = (wave >> 1) * 32;   // wave row offset (0 or 32)
    const int wn   = (wave & 1) * 64;    // wave col offset (0 or 64)

    const int arow = t >> 2;
    const int acol = (t & 3) * 8;
    const int brow = t >> 1;
    const int bcol = (t & 1) * 16;

    f32x4 acc[2][4] = {};

    for (int kt = 0; kt < EMB_DIM / 32; ++kt) {
        const int k0 = kt * 32;
        {
            const float4* srcA = (const float4*)(X + (size_t)(M0 + arow) * EMB_DIM + k0 + acol);
            float4 va0 = srcA[0], va1 = srcA[1];
            unsigned int pa[4];
            pa[0] = (unsigned int)f2bf(va0.x) | ((unsigned int)f2bf(va0.y) << 16);
            pa[1] = (unsigned int)f2bf(va0.z) | ((unsigned int)f2bf(va0.w) << 16);
            pa[2] = (unsigned int)f2bf(va1.x) | ((unsigned int)f2bf(va1.y) << 16);
            pa[3] = (unsigned int)f2bf(va1.z) | ((unsigned int)f2bf(va1.w) << 16);
            *(uint4*)&As[arow][acol] = make_uint4(pa[0], pa[1], pa[2], pa[3]);

            const float4* srcB = (const float4*)(W + (size_t)(N0 + brow) * EMB_DIM + k0 + bcol);
            unsigned int pb[8];
            #pragma unroll
            for (int c = 0; c < 4; ++c) {
                float4 vb = srcB[c];
                pb[c * 2 + 0] = (unsigned int)f2bf(vb.x) | ((unsigned int)f2bf(vb.y) << 16);
                pb[c * 2 + 1] = (unsigned int)f2bf(vb.z) | ((unsigned int)f2bf(vb.w) << 16);
            }
            uint4* dstB = (uint4*)&Bs[brow][bcol];
            dstB[0] = make_uint4(pb[0], pb[1], pb[2], pb[3]);
            dstB[1] = make_uint4(pb[4], pb[5], pb[6], pb[7]);
        }
        __syncthreads();

        bf16x8 af[2], bff[4];
        #pragma unroll
        for (int i = 0; i < 2; ++i)
            af[i] = __builtin_bit_cast(bf16x8,
                *(const uint4*)&As[wm + i * 16 + (lane & 15)][(lane >> 4) * 8]);
        #pragma unroll
        for (int i = 0; i < 4; ++i)
            bff[i] = __builtin_bit_cast(bf16x8,
                *(const uint4*)&Bs[wn + i * 16 + (lane & 15)][(lane >> 4) * 8]);

        #pragma unroll
        for (int mi = 0; mi < 2; ++mi)
            #pragma unroll
            for (int ni = 0; ni < 4; ++ni)
                acc[mi][ni] = __builtin_amdgcn_mfma_f32_16x16x32_bf16(
                    af[mi], bff[ni], acc[mi][ni], 0, 0, 0);
        __syncthreads();
    }

    // epilogue: +bias, fp32 -> bf16. C/D map: col=lane&15, row=(lane>>4)*4+r
    #pragma unroll
    for (int mi = 0; mi < 2; ++mi) {
        #pragma unroll
        for (int ni = 0; ni < 4; ++ni) {
            const int col = N0 + wn + ni * 16 + (lane & 15);
            const float bval = bias[col];
            #pragma unroll
            for (int r = 0; r < 4; ++r) {
                const int row = M0 + wm + mi * 16 + (lane >> 4) * 4 + r;
                out[(size_t)row * EMB_DIM + col] = f2bf(acc[mi][ni][r] + bval);
            }
        }
    }
}

// ---------------------------------------------------------------------------
// Kernel 2: persistent-pipelined scatter. Each block owns 16 consecutive
// output rows and processes them in a software pipeline whose invariant is:
// NO wait ever forces a store drain (vmcnt retires in order, so every load
// is issued BEFORE any younger store, and every wait targets a load that is
// older than all outstanding stores). Raw s_barrier (no vmcnt(0)) replaces
// __syncthreads. NT stores of row r are issued AFTER the gather loads of
// row r+1 and the sidx/Q prefetch of row r+2, then drain in background
// while row r+1 is computed -> store pipe stays busy, amortizing the
// end-of-block drain convoy that capped the 1-row-per-block versions at
// ~45% write duty.
//
// Numerics identical to the verified kernel: sectored gather (8 lanes/key,
// 16 B each), LDS atomicMax ticket dedup (last write wins), row staged in
// 16 KB LDS, NT row write (NT proven better than plain in R4/R5 A/B).
// ---------------------------------------------------------------------------
__global__ __launch_bounds__(256, 6) void scatter_kernel(
    const unsigned short* __restrict__ Qb,
    const unsigned short* __restrict__ Kb,
    const int* __restrict__ sidx,
    float* __restrict__ out)
{
    __shared__ float rowbuf[N_NODES];   // 16 KB; aliased as uint tickets
    __shared__ int   sIdx[K_SPARSE];

    const int t = threadIdx.x;
    const int j = t & 7;                // sector lane within 8-lane key group
    const int base = blockIdx.x * ROWS_PER_BLOCK;

    unsigned int* tags = (unsigned int*)rowbuf;
    f32x4* rowv = (f32x4*)rowbuf;
    const f32x4 z4 = {0.0f, 0.0f, 0.0f, 0.0f};

    // ---------------- prologue: prime the pipeline for row base ----------------
    int sid_cur = 0;
    if (t < K_SPARSE) sid_cur = sidx[(size_t)base * K_SPARSE + t];
    uint4 qu_cur = *(const uint4*)(Qb + (size_t)(base & (N_NODES - 1)) * EMB_DIM
                                   + (base >> 12) * HEAD_DIM + j * 8);

    // zero rowbuf (tags) + publish sIdx for row base
    #pragma unroll
    for (int i2 = 0; i2 < 4; ++i2) rowv[t + 256 * i2] = z4;
    if (t < K_SPARSE) sIdx[t] = sid_cur;
    lds_barrier();

    // tickets(base): last occurrence wins
    if (t < K_SPARSE) atomicMax(&tags[sid_cur], (unsigned int)(t + 1));

    // gather-issue for row base
    int  kidx[4];
    uint4 u[4];
    {
        const int h0 = base >> 12;
        #pragma unroll
        for (int p = 0; p < 4; ++p) {
            const int kk = (t >> 3) + 32 * p;
            kidx[p] = sIdx[kk];
            u[p] = *(const uint4*)(Kb + (size_t)kidx[p] * EMB_DIM + h0 * HEAD_DIM + j * 8);
        }
    }

    // prefetch sidx/Q for row base+1
    int sid_nxt = 0;
    {
        const int r1 = base + 1;
        if (t < K_SPARSE) sid_nxt = sidx[(size_t)r1 * K_SPARSE + t];
    }
    uint4 qu_nxt = *(const uint4*)(Qb + (size_t)((base + 1) & (N_NODES - 1)) * EMB_DIM
                                   + ((base + 1) >> 12) * HEAD_DIM + j * 8);

    // ---------------- main loop: one output row per iteration ----------------
    #pragma unroll 1
    for (int i = 0; i < ROWS_PER_BLOCK; ++i) {
        const int r = base + i;

        // ---- dots for row r (u[] in flight; wait is older than all stores) ----
        float q[8];
        {
            unsigned int uu[4] = {qu_cur.x, qu_cur.y, qu_cur.z, qu_cur.w};
            #pragma unroll
            for (int w = 0; w < 4; ++w) {
                q[2 * w + 0] = bf2f((unsigned short)(uu[w] & 0xffffu));
                q[2 * w + 1] = bf2f((unsigned short)(uu[w] >> 16));
            }
        }
        float score[4];
        #pragma unroll
        for (int p = 0; p < 4; ++p) {
            unsigned int uu[4] = {u[p].x, u[p].y, u[p].z, u[p].w};
            float acc = 0.0f;
            #pragma unroll
            for (int w = 0; w < 4; ++w) {
                acc += bf2f((unsigned short)(uu[w] & 0xffffu)) * q[2 * w + 0];
                acc += bf2f((unsigned short)(uu[w] >> 16))     * q[2 * w + 1];
            }
            acc += __shfl_xor(acc, 1);
            acc += __shfl_xor(acc, 2);
            acc += __shfl_xor(acc, 4);
            score[p] = acc * 0.125f;   // 1/sqrt(64)
        }

        // ---- dedup win-check + scatter scores into rowbuf ----
        lds_barrier();                 // all tickets(r) visible
        unsigned int winmask = 0;
        if (j == 0) {
            #pragma unroll
            for (int p = 0; p < 4; ++p) {
                const int kk = (t >> 3) + 32 * p;
                if (tags[kidx[p]] == (unsigned int)(kk + 1)) winmask |= (1u << p);
            }
        }
        lds_barrier();                 // all tag reads done before overwrite
        if (j == 0) {
            #pragma unroll
            for (int p = 0; p < 4; ++p)
                if (winmask & (1u << p)) rowbuf[kidx[p]] = score[p];
        }
        lds_barrier();                 // scatter writes visible

        // ---- stage row r into registers; rowbuf becomes free ----
        f32x4 v0 = rowv[t];
        f32x4 v1 = rowv[t + 256];
        f32x4 v2 = rowv[t + 512];
        f32x4 v3 = rowv[t + 768];
        lds_barrier();                 // all reads done; rowbuf reusable

        // ---- prep row r+1: zero tags + publish its sIdx ----
        // (sid_nxt/qu_nxt loads are older than the outstanding stores of
        //  row r-1, so these waits do not drain the store queue)
        #pragma unroll
        for (int i2 = 0; i2 < 4; ++i2) rowv[t + 256 * i2] = z4;
        if (t < K_SPARSE) sIdx[t] = sid_nxt;
        lds_barrier();

        // tickets(r+1)
        if (t < K_SPARSE) atomicMax(&tags[sid_nxt], (unsigned int)(t + 1));

        // ---- gather-issue for row r+1 + prefetch sidx/Q for row r+2 ----
        const int in1 = (i + 1 < ROWS_PER_BLOCK) ? i + 1 : ROWS_PER_BLOCK - 1;
        const int rn  = base + in1;
        const int hn  = rn >> 12;
        #pragma unroll
        for (int p = 0; p < 4; ++p) {
            const int kk = (t >> 3) + 32 * p;
            kidx[p] = sIdx[kk];
            u[p] = *(const uint4*)(Kb + (size_t)kidx[p] * EMB_DIM + hn * HEAD_DIM + j * 8);
        }
        const int in2 = (i + 2 < ROWS_PER_BLOCK) ? i + 2 : ROWS_PER_BLOCK - 1;
        const int rf  = base + in2;
        int sid_fut = 0;
        if (t < K_SPARSE) sid_fut = sidx[(size_t)rf * K_SPARSE + t];
        uint4 qu_fut = *(const uint4*)(Qb + (size_t)(rf & (N_NODES - 1)) * EMB_DIM
                                       + (rf >> 12) * HEAD_DIM + j * 8);

        // pin issue order: all loads above stay OLDER than the stores below
        __builtin_amdgcn_sched_barrier(0);

        // ---- NT stores of row r (drain in background; nothing waits on them) ----
        f32x4* orowv = (f32x4*)(out + (size_t)r * N_NODES);
        __builtin_nontemporal_store(v0, &orowv[t]);
        __builtin_nontemporal_store(v1, &orowv[t + 256]);
        __builtin_nontemporal_store(v2, &orowv[t + 512]);
        __builtin_nontemporal_store(v3, &orowv[t + 768]);

        // rotate prefetch registers
        qu_cur = qu_nxt; qu_nxt = qu_fut; sid_nxt = sid_fut;
    }
}

extern "C" void kernel_launch(void* const* d_in, const int* in_sizes, int n_in,
                              void* d_out, int out_size, void* d_ws, size_t ws_size,
                              hipStream_t stream) {
    const float* emb = (const float*)d_in[0];
    const float* Wq  = (const float*)d_in[1];
    const float* bq  = (const float*)d_in[2];
    const float* Wk  = (const float*)d_in[3];
    const float* bk  = (const float*)d_in[4];
    const int*   si  = (const int*)d_in[5];
    float* out = (float*)d_out;

    // workspace: Qb (4 MB) + Kb (4 MB) bf16
    unsigned short* Qb = (unsigned short*)d_ws;
    unsigned short* Kb = Qb + (size_t)N_NODES * EMB_DIM;

    dim3 pg(N_NODES / 64, EMB_DIM / 128, 2);   // 64 x 4 x 2 = 512 blocks
    proj_kernel<<<pg, 256, 0, stream>>>(emb, Wq, bq, Wk, bk, Qb, Kb);

    scatter_kernel<<<SCATTER_BLOCKS, 256, 0, stream>>>(Qb, Kb, si, out);
}